// Round 3
// baseline (18459.166 us; speedup 1.0000x reference)
//
#include <hip/hip_runtime.h>

typedef _Float16 f16x8 __attribute__((ext_vector_type(8)));
typedef float    f32x4 __attribute__((ext_vector_type(4)));

#define DEVINL __device__ __forceinline__

namespace {
constexpr int Tt = 256, Ff = 128, Hh = 256, Uu = 512, OUTo = 128;
constexpr int BT = 16;                   // rows per cluster
constexpr int NCLUST = 32;               // 512 / 16
constexpr int CBLK = 8;                  // blocks per cluster
constexpr int NSLOT = 68;                // frags per (cb, wave): 12 W1 + 16 W2 + 32 heads + 8 Wout
constexpr int NFRAG = CBLK * 4 * NSLOT;  // 2176 fragments
constexpr size_t WFRAG_BYTES = (size_t)NFRAG * 1024;          // 2,228,224
constexpr size_t ACT_OFF = WFRAG_BYTES;
constexpr size_t ACT_STRIDE = 40960;     // z1 16K | z2 16K | h 8K  (+pad)
constexpr size_t CNT_OFF = ACT_OFF + (size_t)NCLUST * ACT_STRIDE;  // 3,538,944
constexpr size_t CNT_BYTES = (size_t)NCLUST * Tt * 3 * 4;          // 98,304
}

// ---- weight prep: f32 row-major -> per-(cb,wave) fp16 MFMA fragment banks ----
// frag elem(l,j) = W[kt*32 + (l>>4)*8 + j][col(nt, l&15)]
__global__ void prep_weights(const float* __restrict__ W1, const float* __restrict__ W2,
                             const float* __restrict__ Wff1, const float* __restrict__ Wff2,
                             const float* __restrict__ Wta, const float* __restrict__ Wtb,
                             const float* __restrict__ Wout, _Float16* __restrict__ ws)
{
    int o = blockIdx.x * blockDim.x + threadIdx.x;
    if (o >= NFRAG * 512) return;
    int j = o & 7, l = (o >> 3) & 63, r = o >> 9;
    int slot = r % NSLOT, bw = r / NSLOT;
    int w = bw & 3, cb = bw >> 2;
    int k_in = ((l >> 4) << 3) + j, lc = l & 15;
    float v;
    if (slot < 12) {
        int kt = slot;
        v = W1[(kt * 32 + k_in) * Uu + cb * 64 + w * 16 + lc];
    } else if (slot < 28) {
        int kt = slot - 12;
        v = W2[(kt * 32 + k_in) * Uu + cb * 64 + w * 16 + lc];
    } else if (slot < 60) {
        int s = slot - 28, hpL = s >> 4, kt = s & 15;
        int head = (w & 1) * 2 + hpL;
        const float* W = (head == 0) ? Wff1 : (head == 1) ? Wff2 : (head == 2) ? Wta : Wtb;
        v = W[(kt * 32 + k_in) * Hh + cb * 32 + (w >> 1) * 16 + lc];
    } else {
        int kt = slot - 60;
        v = Wout[(kt * 32 + k_in) * OUTo + cb * 16 + lc];
    }
    ws[o] = (_Float16)v;
}

DEVINL float fast_tanh(float v) {
    float e = __expf(2.0f * v);
    return 1.0f - 2.0f / (e + 1.0f);
}
DEVINL float fast_sigmoid(float v) { return 1.0f / (1.0f + __expf(-v)); }
DEVINL float lecun_act(float v)    { return 1.7159f * fast_tanh(0.666f * v); }

// cluster barrier: monotonic counter, 8 arrivals, agent scope
DEVINL void cl_sync(int* c) {
    __builtin_amdgcn_fence(__ATOMIC_RELEASE, "agent");
    __syncthreads();
    if (threadIdx.x == 0) {
        __hip_atomic_fetch_add(c, 1, __ATOMIC_RELAXED, __HIP_MEMORY_SCOPE_AGENT);
        while (__hip_atomic_load(c, __ATOMIC_RELAXED, __HIP_MEMORY_SCOPE_AGENT) < CBLK) {}
    }
    __syncthreads();
    __builtin_amdgcn_fence(__ATOMIC_ACQUIRE, "agent");
}

__global__ __launch_bounds__(256, 1)
void cfc_main(const float* __restrict__ x, const float* __restrict__ ts,
              const float* __restrict__ b1g, const float* __restrict__ b2g,
              const float* __restrict__ bff1g, const float* __restrict__ bff2g,
              const float* __restrict__ btag, const float* __restrict__ btbg,
              const float* __restrict__ boutg,
              const _Float16* __restrict__ wsf,
              char* __restrict__ actbase, int* __restrict__ cntbase,
              float* __restrict__ out)
{
    __shared__ float taL[2][2][16][17];   // [hcol-nt][ta/tb][row][col(+pad)]

    const int tid = threadIdx.x;
    const int l = tid & 63, w = tid >> 6;         // 4 waves
    const int lc = l & 15, lg = l >> 4;
    const int cluster = blockIdx.x & 31;          // stride-32 members share an XCD
    const int cb = blockIdx.x >> 5;
    const int r0 = cluster * BT;

    // ---- weight fragments -> registers (persist whole kernel) ----
    const _Float16* wb = wsf + ((size_t)(cb * 4 + w) * NSLOT) * 512 + l * 8;
    f16x8 w1f[12], w2f[16], whf[32], wof[8];
#pragma unroll
    for (int s = 0; s < 12; ++s) w1f[s] = *(const f16x8*)(wb + s * 512);
#pragma unroll
    for (int s = 0; s < 16; ++s) w2f[s] = *(const f16x8*)(wb + (12 + s) * 512);
#pragma unroll
    for (int s = 0; s < 32; ++s) whf[s] = *(const f16x8*)(wb + (28 + s) * 512);
#pragma unroll
    for (int s = 0; s < 8; ++s)  wof[s] = *(const f16x8*)(wb + (60 + s) * 512);

    // ---- per-lane biases ----
    const int colU = cb * 64 + w * 16 + lc;       // W1/W2 output col
    const int hcol = cb * 32 + (w >> 1) * 16 + lc;
    const int colO = cb * 16 + lc;
    const float b1c = b1g[colU], b2c = b2g[colU];
    const float bf1c = bff1g[hcol], bf2c = bff2g[hcol];
    const float btac = btag[hcol], btbc = btbg[hcol];
    const float boc = boutg[colO];

    char* act = actbase + (size_t)cluster * ACT_STRIDE;
    _Float16* z1g = (_Float16*)act;               // [16][512]
    _Float16* z2g = (_Float16*)(act + 16384);     // [16][512]
    _Float16* hg  = (_Float16*)(act + 32768);     // [16][256]
    int* cnt = cntbase + cluster * (Tt * 3);

    f16x8 hfrag[8];                               // h(t-1) A-fragments, start at 0
#pragma unroll
    for (int s = 0; s < 8; ++s) hfrag[s] = f16x8{0,0,0,0,0,0,0,0};

    const int isOdd = w & 1;

    for (int t = 0; t < Tt; ++t) {
        // ---------- phase 1: z1 = lecun([x|h] @ W1 + b1) ----------
        {
            const float* xr = x + ((size_t)(r0 + lc) * Tt + t) * Ff + lg * 8;
            f32x4 aA = {0.f,0.f,0.f,0.f}, aB = {0.f,0.f,0.f,0.f};
#pragma unroll
            for (int kt = 0; kt < 4; ++kt) {
                f32x4 xa = *(const f32x4*)(xr + kt * 32);
                f32x4 xb = *(const f32x4*)(xr + kt * 32 + 4);
                f16x8 af;
#pragma unroll
                for (int q = 0; q < 4; ++q) { af[q] = (_Float16)xa[q]; af[4 + q] = (_Float16)xb[q]; }
                if (kt & 1) aB = __builtin_amdgcn_mfma_f32_16x16x32_f16(af, w1f[kt], aB, 0, 0, 0);
                else        aA = __builtin_amdgcn_mfma_f32_16x16x32_f16(af, w1f[kt], aA, 0, 0, 0);
            }
#pragma unroll
            for (int kt = 4; kt < 12; ++kt) {
                if (kt & 1) aB = __builtin_amdgcn_mfma_f32_16x16x32_f16(hfrag[kt - 4], w1f[kt], aB, 0, 0, 0);
                else        aA = __builtin_amdgcn_mfma_f32_16x16x32_f16(hfrag[kt - 4], w1f[kt], aA, 0, 0, 0);
            }
#pragma unroll
            for (int i = 0; i < 4; ++i)
                z1g[(lg * 4 + i) * Uu + colU] = (_Float16)lecun_act(aA[i] + aB[i] + b1c);
        }
        cl_sync(&cnt[t * 3 + 0]);
        // ---------- phase 2: z2 = lecun(z1 @ W2 + b2) ----------
        {
            f16x8 zf[16];
#pragma unroll
            for (int kt = 0; kt < 16; ++kt)
                zf[kt] = *(const f16x8*)(z1g + lc * Uu + kt * 32 + lg * 8);
            f32x4 aA = {0.f,0.f,0.f,0.f}, aB = {0.f,0.f,0.f,0.f};
#pragma unroll
            for (int kt = 0; kt < 16; ++kt) {
                if (kt & 1) aB = __builtin_amdgcn_mfma_f32_16x16x32_f16(zf[kt], w2f[kt], aB, 0, 0, 0);
                else        aA = __builtin_amdgcn_mfma_f32_16x16x32_f16(zf[kt], w2f[kt], aA, 0, 0, 0);
            }
#pragma unroll
            for (int i = 0; i < 4; ++i)
                z2g[(lg * 4 + i) * Uu + colU] = (_Float16)lecun_act(aA[i] + aB[i] + b2c);
        }
        cl_sync(&cnt[t * 3 + 1]);
        // ---------- phase 3: heads + gate -> h(t) ----------
        {
            f16x8 zf[16];
#pragma unroll
            for (int kt = 0; kt < 16; ++kt)
                zf[kt] = *(const f16x8*)(z2g + lc * Uu + kt * 32 + lg * 8);
            f32x4 aA = {0.f,0.f,0.f,0.f}, aB = {0.f,0.f,0.f,0.f};
#pragma unroll
            for (int kt = 0; kt < 16; ++kt) {
                aA = __builtin_amdgcn_mfma_f32_16x16x32_f16(zf[kt], whf[kt], aA, 0, 0, 0);
                aB = __builtin_amdgcn_mfma_f32_16x16x32_f16(zf[kt], whf[16 + kt], aB, 0, 0, 0);
            }
            if (isOdd) {    // heads 2,3 = ta, tb -> LDS
#pragma unroll
                for (int i = 0; i < 4; ++i) {
                    taL[w >> 1][0][lg * 4 + i][lc] = aA[i] + btac;
                    taL[w >> 1][1][lg * 4 + i][lc] = aB[i] + btbc;
                }
            }
            __syncthreads();
            if (!isOdd) {   // heads 0,1 = ff1, ff2 + gate + h store
                float tsv[4];
#pragma unroll
                for (int i = 0; i < 4; ++i)
                    tsv[i] = ts[(size_t)(r0 + lg * 4 + i) * Tt + t];
#pragma unroll
                for (int i = 0; i < 4; ++i) {
                    int row = lg * 4 + i;
                    float ff1 = fast_tanh(aA[i] + bf1c);
                    float ff2 = fast_tanh(aB[i] + bf2c);
                    float ta = taL[w >> 1][0][row][lc];
                    float tb = taL[w >> 1][1][row][lc];
                    float s = fast_sigmoid(ta * (tsv[i] * (1.0f / 256.0f)) + tb);
                    hg[row * Hh + hcol] = (_Float16)(ff1 + s * (ff2 - ff1));
                }
            }
        }
        cl_sync(&cnt[t * 3 + 2]);
        // ---------- phase 4: out(t) = h @ Wout + bout; reload h frags ----------
        {
#pragma unroll
            for (int kt = 0; kt < 8; ++kt)
                hfrag[kt] = *(const f16x8*)(hg + lc * Hh + kt * 32 + lg * 8);
            if (w == 0) {
                f32x4 aA = {0.f,0.f,0.f,0.f}, aB = {0.f,0.f,0.f,0.f};
#pragma unroll
                for (int kt = 0; kt < 8; ++kt) {
                    if (kt & 1) aB = __builtin_amdgcn_mfma_f32_16x16x32_f16(hfrag[kt], wof[kt], aB, 0, 0, 0);
                    else        aA = __builtin_amdgcn_mfma_f32_16x16x32_f16(hfrag[kt], wof[kt], aA, 0, 0, 0);
                }
#pragma unroll
                for (int i = 0; i < 4; ++i)
                    out[((size_t)(r0 + lg * 4 + i) * Tt + t) * OUTo + colO] = aA[i] + aB[i] + boc;
            }
        }
        // no sync needed: next phase-1 z1 writes are gated by cnt[t*3+2] ordering
    }
}

extern "C" void kernel_launch(void* const* d_in, const int* in_sizes, int n_in,
                              void* d_out, int out_size, void* d_ws, size_t ws_size,
                              hipStream_t stream) {
    const float* x    = (const float*)d_in[0];
    const float* ts   = (const float*)d_in[1];
    const float* W1   = (const float*)d_in[2];
    const float* b1   = (const float*)d_in[3];
    const float* W2   = (const float*)d_in[4];
    const float* b2   = (const float*)d_in[5];
    const float* Wff1 = (const float*)d_in[6];
    const float* bff1 = (const float*)d_in[7];
    const float* Wff2 = (const float*)d_in[8];
    const float* bff2 = (const float*)d_in[9];
    const float* Wta  = (const float*)d_in[10];
    const float* bta  = (const float*)d_in[11];
    const float* Wtb  = (const float*)d_in[12];
    const float* btb  = (const float*)d_in[13];
    const float* Wout = (const float*)d_in[14];
    const float* bout = (const float*)d_in[15];
    float* out = (float*)d_out;

    _Float16* wf = (_Float16*)d_ws;
    char* act = (char*)d_ws + ACT_OFF;
    int* cnt = (int*)((char*)d_ws + CNT_OFF);

    hipMemsetAsync(cnt, 0, CNT_BYTES, stream);
    prep_weights<<<(NFRAG * 512) / 256, 256, 0, stream>>>(W1, W2, Wff1, Wff2, Wta, Wtb, Wout, wf);
    cfc_main<<<NCLUST * CBLK, 256, 0, stream>>>(x, ts, b1, b2, bff1, bff2, bta, btb, bout,
                                                wf, act, cnt, out);
}

// Round 4
// 3874.759 us; speedup vs baseline: 4.7640x; 4.7640x over previous
//
#include <hip/hip_runtime.h>

typedef _Float16 f16x8 __attribute__((ext_vector_type(8)));
typedef float    f32x4 __attribute__((ext_vector_type(4)));

#define DEVINL __device__ __forceinline__

namespace {
constexpr int Tt = 256, Ff = 128, Hh = 256, Uu = 512, OUTo = 128;
constexpr int BT = 16;                   // rows per cluster
constexpr int NCLUST = 32;               // 512 / 16
constexpr int CBLK = 8;                  // blocks per cluster
constexpr int NSLOT = 68;                // frags per (cb, wave): 12 W1 + 16 W2 + 32 heads + 8 Wout
constexpr int NFRAG = CBLK * 4 * NSLOT;  // 2176 fragments
constexpr size_t WFRAG_BYTES = (size_t)NFRAG * 1024;
constexpr size_t ACT_OFF = WFRAG_BYTES;
constexpr size_t ACT_STRIDE = 40960;     // z1 16K | z2 16K | h 8K (+pad)
constexpr size_t CNT_OFF = ACT_OFF + (size_t)NCLUST * ACT_STRIDE;
constexpr size_t CNT_BYTES = (size_t)NCLUST * Tt * 3 * 4;
}

// ---- weight prep: f32 row-major -> per-(cb,wave) fp16 MFMA fragment banks ----
__global__ void prep_weights(const float* __restrict__ W1, const float* __restrict__ W2,
                             const float* __restrict__ Wff1, const float* __restrict__ Wff2,
                             const float* __restrict__ Wta, const float* __restrict__ Wtb,
                             const float* __restrict__ Wout, _Float16* __restrict__ ws)
{
    int o = blockIdx.x * blockDim.x + threadIdx.x;
    if (o >= NFRAG * 512) return;
    int j = o & 7, l = (o >> 3) & 63, r = o >> 9;
    int slot = r % NSLOT, bw = r / NSLOT;
    int w = bw & 3, cb = bw >> 2;
    int k_in = ((l >> 4) << 3) + j, lc = l & 15;
    float v;
    if (slot < 12) {
        int kt = slot;
        v = W1[(kt * 32 + k_in) * Uu + cb * 64 + w * 16 + lc];
    } else if (slot < 28) {
        int kt = slot - 12;
        v = W2[(kt * 32 + k_in) * Uu + cb * 64 + w * 16 + lc];
    } else if (slot < 60) {
        int s = slot - 28, hpL = s >> 4, kt = s & 15;
        int head = (w & 1) * 2 + hpL;
        const float* W = (head == 0) ? Wff1 : (head == 1) ? Wff2 : (head == 2) ? Wta : Wtb;
        v = W[(kt * 32 + k_in) * Hh + cb * 32 + (w >> 1) * 16 + lc];
    } else {
        int kt = slot - 60;
        v = Wout[(kt * 32 + k_in) * OUTo + cb * 16 + lc];
    }
    ws[o] = (_Float16)v;
}

DEVINL float fast_tanh(float v) {
    float e = __expf(2.0f * v);
    return 1.0f - 2.0f / (e + 1.0f);
}
DEVINL float fast_sigmoid(float v) { return 1.0f / (1.0f + __expf(-v)); }
DEVINL float lecun_act(float v)    { return 1.7159f * fast_tanh(0.666f * v); }

// ---- system-scope (MALL-coherent, L2-bypass) accessors: NO fences, no wbl2 ----
DEVINL void st2_sys(_Float16* p, _Float16 v) {
    union { _Float16 f; unsigned short u; } c; c.f = v;
    __hip_atomic_store((unsigned short*)p, c.u, __ATOMIC_RELAXED, __HIP_MEMORY_SCOPE_SYSTEM);
}
DEVINL unsigned long long ld8_sys(const void* p) {
    return __hip_atomic_load((unsigned long long*)p, __ATOMIC_RELAXED, __HIP_MEMORY_SCOPE_SYSTEM);
}
DEVINL f16x8 ldfrag_sys(const _Float16* p) {
    union { unsigned long long u[2]; f16x8 f; } c;
    c.u[0] = ld8_sys(p);
    c.u[1] = ld8_sys(p + 4);
    return c.f;
}

// cluster barrier: per-thread store-drain, then one monotonic system-scope add + poll.
DEVINL void cl_sync(int* c) {
    asm volatile("s_waitcnt vmcnt(0)" ::: "memory");   // all my sc1 stores are visible
    __syncthreads();
    if (threadIdx.x == 0) {
        __hip_atomic_fetch_add(c, 1, __ATOMIC_RELAXED, __HIP_MEMORY_SCOPE_SYSTEM);
        while (__hip_atomic_load(c, __ATOMIC_RELAXED, __HIP_MEMORY_SCOPE_SYSTEM) < CBLK) {}
    }
    __syncthreads();
    asm volatile("" ::: "memory");
}

__global__ __launch_bounds__(256, 1)
void cfc_main(const float* __restrict__ x, const float* __restrict__ ts,
              const float* __restrict__ b1g, const float* __restrict__ b2g,
              const float* __restrict__ bff1g, const float* __restrict__ bff2g,
              const float* __restrict__ btag, const float* __restrict__ btbg,
              const float* __restrict__ boutg,
              const _Float16* __restrict__ wsf,
              char* __restrict__ actbase, int* __restrict__ cntbase,
              float* __restrict__ out)
{
    __shared__ float taL[2][2][16][17];

    const int tid = threadIdx.x;
    const int l = tid & 63, w = tid >> 6;         // 4 waves
    const int lc = l & 15, lg = l >> 4;
    const int cluster = blockIdx.x & 31;
    const int cb = blockIdx.x >> 5;
    const int r0 = cluster * BT;

    // ---- weight fragments -> registers, pinned for the whole kernel ----
    const _Float16* wb = wsf + ((size_t)(cb * 4 + w) * NSLOT) * 512 + l * 8;
    f16x8 w1f[12], w2f[16], whf[32], wof[8];
#pragma unroll
    for (int s = 0; s < 12; ++s) w1f[s] = *(const f16x8*)(wb + s * 512);
#pragma unroll
    for (int s = 0; s < 16; ++s) w2f[s] = *(const f16x8*)(wb + (12 + s) * 512);
#pragma unroll
    for (int s = 0; s < 32; ++s) whf[s] = *(const f16x8*)(wb + (28 + s) * 512);
#pragma unroll
    for (int s = 0; s < 8; ++s)  wof[s] = *(const f16x8*)(wb + (60 + s) * 512);
#pragma unroll
    for (int s = 0; s < 12; ++s) asm volatile("" : "+v"(w1f[s]));
#pragma unroll
    for (int s = 0; s < 16; ++s) asm volatile("" : "+v"(w2f[s]));
#pragma unroll
    for (int s = 0; s < 32; ++s) asm volatile("" : "+v"(whf[s]));
#pragma unroll
    for (int s = 0; s < 8; ++s)  asm volatile("" : "+v"(wof[s]));

    // ---- per-lane biases ----
    const int colU = cb * 64 + w * 16 + lc;
    const int hcol = cb * 32 + (w >> 1) * 16 + lc;
    const int colO = cb * 16 + lc;
    const float b1c = b1g[colU], b2c = b2g[colU];
    const float bf1c = bff1g[hcol], bf2c = bff2g[hcol];
    const float btac = btag[hcol], btbc = btbg[hcol];
    const float boc = boutg[colO];

    char* act = actbase + (size_t)cluster * ACT_STRIDE;
    _Float16* z1g = (_Float16*)act;               // [16][512]
    _Float16* z2g = (_Float16*)(act + 16384);     // [16][512]
    _Float16* hg  = (_Float16*)(act + 32768);     // [16][256]
    int* cnt = cntbase + cluster * (Tt * 3);

    f16x8 hfrag[8];
#pragma unroll
    for (int s = 0; s < 8; ++s) hfrag[s] = f16x8{0,0,0,0,0,0,0,0};

    // x A-fragments for current step (prefetched during previous phase 4)
    f16x8 xf[4];
    {
        const float* xr = x + ((size_t)(r0 + lc) * Tt + 0) * Ff + lg * 8;
#pragma unroll
        for (int kt = 0; kt < 4; ++kt) {
            f32x4 xa = *(const f32x4*)(xr + kt * 32);
            f32x4 xb = *(const f32x4*)(xr + kt * 32 + 4);
            f16x8 af;
#pragma unroll
            for (int q = 0; q < 4; ++q) { af[q] = (_Float16)xa[q]; af[4 + q] = (_Float16)xb[q]; }
            xf[kt] = af;
        }
    }

    const int isOdd = w & 1;

    for (int t = 0; t < Tt; ++t) {
        // ---------- phase 1: z1 = lecun([x|h] @ W1 + b1) ----------
        {
            f32x4 aA = {0.f,0.f,0.f,0.f}, aB = {0.f,0.f,0.f,0.f};
#pragma unroll
            for (int kt = 0; kt < 4; ++kt) {
                if (kt & 1) aB = __builtin_amdgcn_mfma_f32_16x16x32_f16(xf[kt], w1f[kt], aB, 0, 0, 0);
                else        aA = __builtin_amdgcn_mfma_f32_16x16x32_f16(xf[kt], w1f[kt], aA, 0, 0, 0);
            }
#pragma unroll
            for (int kt = 4; kt < 12; ++kt) {
                if (kt & 1) aB = __builtin_amdgcn_mfma_f32_16x16x32_f16(hfrag[kt - 4], w1f[kt], aB, 0, 0, 0);
                else        aA = __builtin_amdgcn_mfma_f32_16x16x32_f16(hfrag[kt - 4], w1f[kt], aA, 0, 0, 0);
            }
#pragma unroll
            for (int i = 0; i < 4; ++i)
                st2_sys(&z1g[(lg * 4 + i) * Uu + colU], (_Float16)lecun_act(aA[i] + aB[i] + b1c));
        }
        cl_sync(&cnt[t * 3 + 0]);
        // ---------- phase 2: z2 = lecun(z1 @ W2 + b2) ----------
        {
            f16x8 zf[16];
#pragma unroll
            for (int kt = 0; kt < 16; ++kt)
                zf[kt] = ldfrag_sys(z1g + lc * Uu + kt * 32 + lg * 8);
            f32x4 aA = {0.f,0.f,0.f,0.f}, aB = {0.f,0.f,0.f,0.f};
#pragma unroll
            for (int kt = 0; kt < 16; ++kt) {
                if (kt & 1) aB = __builtin_amdgcn_mfma_f32_16x16x32_f16(zf[kt], w2f[kt], aB, 0, 0, 0);
                else        aA = __builtin_amdgcn_mfma_f32_16x16x32_f16(zf[kt], w2f[kt], aA, 0, 0, 0);
            }
#pragma unroll
            for (int i = 0; i < 4; ++i)
                st2_sys(&z2g[(lg * 4 + i) * Uu + colU], (_Float16)lecun_act(aA[i] + aB[i] + b2c));
        }
        cl_sync(&cnt[t * 3 + 1]);
        // ---------- phase 3: heads + gate -> h(t) ----------
        {
            f16x8 zf[16];
#pragma unroll
            for (int kt = 0; kt < 16; ++kt)
                zf[kt] = ldfrag_sys(z2g + lc * Uu + kt * 32 + lg * 8);
            f32x4 aA = {0.f,0.f,0.f,0.f}, aB = {0.f,0.f,0.f,0.f};
#pragma unroll
            for (int kt = 0; kt < 16; ++kt) {
                aA = __builtin_amdgcn_mfma_f32_16x16x32_f16(zf[kt], whf[kt], aA, 0, 0, 0);
                aB = __builtin_amdgcn_mfma_f32_16x16x32_f16(zf[kt], whf[16 + kt], aB, 0, 0, 0);
            }
            if (isOdd) {
#pragma unroll
                for (int i = 0; i < 4; ++i) {
                    taL[w >> 1][0][lg * 4 + i][lc] = aA[i] + btac;
                    taL[w >> 1][1][lg * 4 + i][lc] = aB[i] + btbc;
                }
            }
            __syncthreads();
            if (!isOdd) {
                float tsv[4];
#pragma unroll
                for (int i = 0; i < 4; ++i)
                    tsv[i] = ts[(size_t)(r0 + lg * 4 + i) * Tt + t];
#pragma unroll
                for (int i = 0; i < 4; ++i) {
                    int row = lg * 4 + i;
                    float ff1 = fast_tanh(aA[i] + bf1c);
                    float ff2 = fast_tanh(aB[i] + bf2c);
                    float ta = taL[w >> 1][0][row][lc];
                    float tb = taL[w >> 1][1][row][lc];
                    float s = fast_sigmoid(ta * (tsv[i] * (1.0f / 256.0f)) + tb);
                    st2_sys(&hg[row * Hh + hcol], (_Float16)(ff1 + s * (ff2 - ff1)));
                }
            }
        }
        cl_sync(&cnt[t * 3 + 2]);
        // ---------- phase 4: out(t) = h @ Wout + bout; h frags; x(t+1) prefetch ----------
        {
#pragma unroll
            for (int kt = 0; kt < 8; ++kt)
                hfrag[kt] = ldfrag_sys(hg + lc * Hh + kt * 32 + lg * 8);
            if (t + 1 < Tt) {
                const float* xr = x + ((size_t)(r0 + lc) * Tt + (t + 1)) * Ff + lg * 8;
#pragma unroll
                for (int kt = 0; kt < 4; ++kt) {
                    f32x4 xa = *(const f32x4*)(xr + kt * 32);
                    f32x4 xb = *(const f32x4*)(xr + kt * 32 + 4);
                    f16x8 af;
#pragma unroll
                    for (int q = 0; q < 4; ++q) { af[q] = (_Float16)xa[q]; af[4 + q] = (_Float16)xb[q]; }
                    xf[kt] = af;
                }
            }
            if (w == 0) {
                f32x4 aA = {0.f,0.f,0.f,0.f}, aB = {0.f,0.f,0.f,0.f};
#pragma unroll
                for (int kt = 0; kt < 8; ++kt) {
                    if (kt & 1) aB = __builtin_amdgcn_mfma_f32_16x16x32_f16(hfrag[kt], wof[kt], aB, 0, 0, 0);
                    else        aA = __builtin_amdgcn_mfma_f32_16x16x32_f16(hfrag[kt], wof[kt], aA, 0, 0, 0);
                }
#pragma unroll
                for (int i = 0; i < 4; ++i)
                    out[((size_t)(r0 + lg * 4 + i) * Tt + t) * OUTo + colO] = aA[i] + aB[i] + boc;
            }
        }
        // next-step z1 writes are ordered behind cnt[t*3+2]
    }
}

extern "C" void kernel_launch(void* const* d_in, const int* in_sizes, int n_in,
                              void* d_out, int out_size, void* d_ws, size_t ws_size,
                              hipStream_t stream) {
    const float* x    = (const float*)d_in[0];
    const float* ts   = (const float*)d_in[1];
    const float* W1   = (const float*)d_in[2];
    const float* b1   = (const float*)d_in[3];
    const float* W2   = (const float*)d_in[4];
    const float* b2   = (const float*)d_in[5];
    const float* Wff1 = (const float*)d_in[6];
    const float* bff1 = (const float*)d_in[7];
    const float* Wff2 = (const float*)d_in[8];
    const float* bff2 = (const float*)d_in[9];
    const float* Wta  = (const float*)d_in[10];
    const float* bta  = (const float*)d_in[11];
    const float* Wtb  = (const float*)d_in[12];
    const float* btb  = (const float*)d_in[13];
    const float* Wout = (const float*)d_in[14];
    const float* bout = (const float*)d_in[15];
    float* out = (float*)d_out;

    _Float16* wf = (_Float16*)d_ws;
    char* act = (char*)d_ws + ACT_OFF;
    int* cnt = (int*)((char*)d_ws + CNT_OFF);

    hipMemsetAsync(cnt, 0, CNT_BYTES, stream);
    prep_weights<<<(NFRAG * 512) / 256, 256, 0, stream>>>(W1, W2, Wff1, Wff2, Wta, Wtb, Wout, wf);
    cfc_main<<<NCLUST * CBLK, 256, 0, stream>>>(x, ts, b1, b2, bff1, bff2, bta, btb, bout,
                                                wf, act, cnt, out);
}

// Round 6
// 2919.718 us; speedup vs baseline: 6.3222x; 1.3271x over previous
//
#include <hip/hip_runtime.h>

typedef _Float16 f16x8 __attribute__((ext_vector_type(8)));
typedef float    f32x4 __attribute__((ext_vector_type(4)));

#define DEVINL __device__ __forceinline__

namespace {
constexpr int Tt = 256, Ff = 128, Hh = 256, Uu = 512, OUTo = 128;
constexpr int BT = 16;                   // rows per cluster
constexpr int NCLUST = 32;               // 512 / 16
constexpr int CBLK = 8;                  // blocks per cluster
constexpr int NSLOT = 68;                // frags per (cb, wave): 12 W1 + 16 W2 + 32 heads + 8 Wout
constexpr int NFRAG = CBLK * 4 * NSLOT;  // 2176 fragments
constexpr size_t WFRAG_BYTES = (size_t)NFRAG * 1024;
constexpr size_t ACT_OFF = WFRAG_BYTES;
constexpr size_t ACT_STRIDE = 40960;     // z1 16K | z2 16K | h 8K (+pad)
constexpr size_t CNT_OFF = ACT_OFF + (size_t)NCLUST * ACT_STRIDE;
constexpr size_t CNT_BYTES = (size_t)NCLUST * 8 * 4;   // 8 flag slots per cluster
}

// ---- weight prep: f32 row-major -> per-(cb,wave) fp16 MFMA fragment banks ----
__global__ void prep_weights(const float* __restrict__ W1, const float* __restrict__ W2,
                             const float* __restrict__ Wff1, const float* __restrict__ Wff2,
                             const float* __restrict__ Wta, const float* __restrict__ Wtb,
                             const float* __restrict__ Wout, _Float16* __restrict__ ws)
{
    int o = blockIdx.x * blockDim.x + threadIdx.x;
    if (o >= NFRAG * 512) return;
    int j = o & 7, l = (o >> 3) & 63, r = o >> 9;
    int slot = r % NSLOT, bw = r / NSLOT;
    int w = bw & 3, cb = bw >> 2;
    int k_in = ((l >> 4) << 3) + j, lc = l & 15;
    float v;
    if (slot < 12) {
        int kt = slot;
        v = W1[(kt * 32 + k_in) * Uu + cb * 64 + w * 16 + lc];
    } else if (slot < 28) {
        int kt = slot - 12;
        v = W2[(kt * 32 + k_in) * Uu + cb * 64 + w * 16 + lc];
    } else if (slot < 60) {
        int s = slot - 28, hpL = s >> 4, kt = s & 15;
        int head = (w & 1) * 2 + hpL;
        const float* W = (head == 0) ? Wff1 : (head == 1) ? Wff2 : (head == 2) ? Wta : Wtb;
        v = W[(kt * 32 + k_in) * Hh + cb * 32 + (w >> 1) * 16 + lc];
    } else {
        int kt = slot - 60;
        v = Wout[(kt * 32 + k_in) * OUTo + cb * 16 + lc];
    }
    ws[o] = (_Float16)v;
}

DEVINL float fast_tanh(float v) {
    float e = __expf(2.0f * v);
    return 1.0f - 2.0f / (e + 1.0f);
}
DEVINL float fast_sigmoid(float v) { return 1.0f / (1.0f + __expf(-v)); }
DEVINL float lecun_act(float v)    { return 1.7159f * fast_tanh(0.666f * v); }

// ---- wide MALL-coherent (sc0 sc1) accessors ----
DEVINL void stg16_sys(_Float16* p, f16x8 v) {
    asm volatile("global_store_dwordx4 %0, %1, off sc0 sc1" :: "v"(p), "v"(v) : "memory");
}

// 16 B-frag batch loads: issue all + waitcnt inside ONE asm (no spill window, 1 RT)
#define LD8_FRAGS(d, base) \
    asm volatile( \
        "global_load_dwordx4 %0, %8, off sc0 sc1\n\t" \
        "global_load_dwordx4 %1, %8, off offset:64 sc0 sc1\n\t" \
        "global_load_dwordx4 %2, %8, off offset:128 sc0 sc1\n\t" \
        "global_load_dwordx4 %3, %8, off offset:192 sc0 sc1\n\t" \
        "global_load_dwordx4 %4, %8, off offset:256 sc0 sc1\n\t" \
        "global_load_dwordx4 %5, %8, off offset:320 sc0 sc1\n\t" \
        "global_load_dwordx4 %6, %8, off offset:384 sc0 sc1\n\t" \
        "global_load_dwordx4 %7, %8, off offset:448 sc0 sc1\n\t" \
        "s_waitcnt vmcnt(0)" \
        : "=&v"(d[0]), "=&v"(d[1]), "=&v"(d[2]), "=&v"(d[3]), \
          "=&v"(d[4]), "=&v"(d[5]), "=&v"(d[6]), "=&v"(d[7]) \
        : "v"(base) : "memory")

#define LD16_FRAGS(d, base) \
    asm volatile( \
        "global_load_dwordx4 %0, %16, off sc0 sc1\n\t" \
        "global_load_dwordx4 %1, %16, off offset:64 sc0 sc1\n\t" \
        "global_load_dwordx4 %2, %16, off offset:128 sc0 sc1\n\t" \
        "global_load_dwordx4 %3, %16, off offset:192 sc0 sc1\n\t" \
        "global_load_dwordx4 %4, %16, off offset:256 sc0 sc1\n\t" \
        "global_load_dwordx4 %5, %16, off offset:320 sc0 sc1\n\t" \
        "global_load_dwordx4 %6, %16, off offset:384 sc0 sc1\n\t" \
        "global_load_dwordx4 %7, %16, off offset:448 sc0 sc1\n\t" \
        "global_load_dwordx4 %8, %16, off offset:512 sc0 sc1\n\t" \
        "global_load_dwordx4 %9, %16, off offset:576 sc0 sc1\n\t" \
        "global_load_dwordx4 %10, %16, off offset:640 sc0 sc1\n\t" \
        "global_load_dwordx4 %11, %16, off offset:704 sc0 sc1\n\t" \
        "global_load_dwordx4 %12, %16, off offset:768 sc0 sc1\n\t" \
        "global_load_dwordx4 %13, %16, off offset:832 sc0 sc1\n\t" \
        "global_load_dwordx4 %14, %16, off offset:896 sc0 sc1\n\t" \
        "global_load_dwordx4 %15, %16, off offset:960 sc0 sc1\n\t" \
        "s_waitcnt vmcnt(0)" \
        : "=&v"(d[0]), "=&v"(d[1]), "=&v"(d[2]), "=&v"(d[3]), \
          "=&v"(d[4]), "=&v"(d[5]), "=&v"(d[6]), "=&v"(d[7]), \
          "=&v"(d[8]), "=&v"(d[9]), "=&v"(d[10]), "=&v"(d[11]), \
          "=&v"(d[12]), "=&v"(d[13]), "=&v"(d[14]), "=&v"(d[15]) \
        : "v"(base) : "memory")

// flag barrier: drain own stores, block-sync, thread0 writes monotone tag + polls all 8
DEVINL void cl_sync(int* flags, int cb, int tag, int tid) {
    asm volatile("s_waitcnt vmcnt(0)" ::: "memory");
    __syncthreads();
    if (tid == 0) {
        asm volatile("global_store_dword %0, %1, off sc0 sc1" :: "v"(flags + cb), "v"(tag) : "memory");
        for (;;) {
            int4 a, b;
            asm volatile("global_load_dwordx4 %0, %2, off sc0 sc1\n\t"
                         "global_load_dwordx4 %1, %2, off offset:16 sc0 sc1\n\t"
                         "s_waitcnt vmcnt(0)"
                         : "=&v"(a), "=&v"(b) : "v"(flags) : "memory");
            int m0 = min(min(a.x, a.y), min(a.z, a.w));
            int m1 = min(min(b.x, b.y), min(b.z, b.w));
            if (min(m0, m1) >= tag) break;
        }
    }
    __syncthreads();
    __builtin_amdgcn_sched_barrier(0);
}

__global__ __launch_bounds__(256, 1)
void cfc_main(const float* __restrict__ x, const float* __restrict__ ts,
              const float* __restrict__ b1g, const float* __restrict__ b2g,
              const float* __restrict__ bff1g, const float* __restrict__ bff2g,
              const float* __restrict__ btag, const float* __restrict__ btbg,
              const float* __restrict__ boutg,
              const _Float16* __restrict__ wsf,
              char* __restrict__ actbase, int* __restrict__ cntbase,
              float* __restrict__ out)
{
    __shared__ float taL[2][2][16][17];
    __shared__ __align__(16) _Float16 xpose[16][72];   // store-transpose tile

    const int tid = threadIdx.x;
    const int l = tid & 63, w = tid >> 6;         // 4 waves
    const int lc = l & 15, lg = l >> 4;
    const int cluster = blockIdx.x & 31;
    const int cb = blockIdx.x >> 5;
    const int r0 = cluster * BT;

    // ---- weight fragments -> registers, pinned ----
    const _Float16* wb = wsf + ((size_t)(cb * 4 + w) * NSLOT) * 512 + l * 8;
    f16x8 w1f[12], w2f[16], whf[32], wof[8];
#pragma unroll
    for (int s = 0; s < 12; ++s) w1f[s] = *(const f16x8*)(wb + s * 512);
#pragma unroll
    for (int s = 0; s < 16; ++s) w2f[s] = *(const f16x8*)(wb + (12 + s) * 512);
#pragma unroll
    for (int s = 0; s < 32; ++s) whf[s] = *(const f16x8*)(wb + (28 + s) * 512);
#pragma unroll
    for (int s = 0; s < 8; ++s)  wof[s] = *(const f16x8*)(wb + (60 + s) * 512);
#pragma unroll
    for (int s = 0; s < 12; ++s) asm volatile("" : "+v"(w1f[s]));
#pragma unroll
    for (int s = 0; s < 16; ++s) asm volatile("" : "+v"(w2f[s]));
#pragma unroll
    for (int s = 0; s < 32; ++s) asm volatile("" : "+v"(whf[s]));
#pragma unroll
    for (int s = 0; s < 8; ++s)  asm volatile("" : "+v"(wof[s]));

    // ---- per-lane biases ----
    const int colU = cb * 64 + w * 16 + lc;
    const int hcol = cb * 32 + (w >> 1) * 16 + lc;
    const int colO = cb * 16 + lc;
    const float b1c = b1g[colU], b2c = b2g[colU];
    const float bf1c = bff1g[hcol], bf2c = bff2g[hcol];
    const float btac = btag[hcol], btbc = btbg[hcol];
    const float boc = boutg[colO];

    char* act = actbase + (size_t)cluster * ACT_STRIDE;
    _Float16* z1g = (_Float16*)act;               // [16][512]
    _Float16* z2g = (_Float16*)(act + 16384);     // [16][512]
    _Float16* hg  = (_Float16*)(act + 32768);     // [16][256]
    int* flags = cntbase + cluster * 8;

    f16x8 hfrag[8];
#pragma unroll
    for (int s = 0; s < 8; ++s) hfrag[s] = f16x8{0,0,0,0,0,0,0,0};

    // x A-fragments for step 0
    f16x8 xf[4];
    {
        const float* xr = x + ((size_t)(r0 + lc) * Tt + 0) * Ff + lg * 8;
#pragma unroll
        for (int kt = 0; kt < 4; ++kt) {
            f32x4 xa = *(const f32x4*)(xr + kt * 32);
            f32x4 xb = *(const f32x4*)(xr + kt * 32 + 4);
            f16x8 af;
#pragma unroll
            for (int q = 0; q < 4; ++q) { af[q] = (_Float16)xa[q]; af[4 + q] = (_Float16)xb[q]; }
            xf[kt] = af;
        }
    }

    const int isOdd = w & 1;

    for (int t = 0; t < Tt; ++t) {
        // ---------- phase 1: z1 = lecun([x|h] @ W1 + b1) ----------
        {
            f32x4 aA = {0.f,0.f,0.f,0.f}, aB = {0.f,0.f,0.f,0.f};
#pragma unroll
            for (int kt = 0; kt < 4; ++kt) {
                if (kt & 1) aB = __builtin_amdgcn_mfma_f32_16x16x32_f16(xf[kt], w1f[kt], aB, 0, 0, 0);
                else        aA = __builtin_amdgcn_mfma_f32_16x16x32_f16(xf[kt], w1f[kt], aA, 0, 0, 0);
            }
#pragma unroll
            for (int kt = 4; kt < 12; ++kt) {
                if (kt & 1) aB = __builtin_amdgcn_mfma_f32_16x16x32_f16(hfrag[kt - 4], w1f[kt], aB, 0, 0, 0);
                else        aA = __builtin_amdgcn_mfma_f32_16x16x32_f16(hfrag[kt - 4], w1f[kt], aA, 0, 0, 0);
            }
#pragma unroll
            for (int i = 0; i < 4; ++i)
                xpose[lg * 4 + i][w * 16 + lc] = (_Float16)lecun_act(aA[i] + aB[i] + b1c);
            __syncthreads();
            if (tid < 128) {
                int row = tid >> 3, seg = tid & 7;
                f16x8 v = *(const f16x8*)&xpose[row][seg * 8];
                stg16_sys(z1g + row * Uu + cb * 64 + seg * 8, v);
            }
        }
        cl_sync(flags, cb, t * 3 + 1, tid);
        // ---------- phase 2: z2 = lecun(z1 @ W2 + b2) ----------
        {
            f16x8 zf[16];
            LD16_FRAGS(zf, z1g + lc * Uu + lg * 8);
            f32x4 aA = {0.f,0.f,0.f,0.f}, aB = {0.f,0.f,0.f,0.f};
#pragma unroll
            for (int kt = 0; kt < 16; ++kt) {
                if (kt & 1) aB = __builtin_amdgcn_mfma_f32_16x16x32_f16(zf[kt], w2f[kt], aB, 0, 0, 0);
                else        aA = __builtin_amdgcn_mfma_f32_16x16x32_f16(zf[kt], w2f[kt], aA, 0, 0, 0);
            }
            __syncthreads();   // xpose reuse guard
#pragma unroll
            for (int i = 0; i < 4; ++i)
                xpose[lg * 4 + i][w * 16 + lc] = (_Float16)lecun_act(aA[i] + aB[i] + b2c);
            __syncthreads();
            if (tid < 128) {
                int row = tid >> 3, seg = tid & 7;
                f16x8 v = *(const f16x8*)&xpose[row][seg * 8];
                stg16_sys(z2g + row * Uu + cb * 64 + seg * 8, v);
            }
        }
        cl_sync(flags, cb, t * 3 + 2, tid);
        // ---------- phase 3: heads + gate -> h(t) ----------
        {
            f16x8 zf[16];
            LD16_FRAGS(zf, z2g + lc * Uu + lg * 8);
            f32x4 aA = {0.f,0.f,0.f,0.f}, aB = {0.f,0.f,0.f,0.f};
#pragma unroll
            for (int kt = 0; kt < 16; ++kt) {
                aA = __builtin_amdgcn_mfma_f32_16x16x32_f16(zf[kt], whf[kt], aA, 0, 0, 0);
                aB = __builtin_amdgcn_mfma_f32_16x16x32_f16(zf[kt], whf[16 + kt], aB, 0, 0, 0);
            }
            if (isOdd) {    // ta, tb -> LDS
#pragma unroll
                for (int i = 0; i < 4; ++i) {
                    taL[w >> 1][0][lg * 4 + i][lc] = aA[i] + btac;
                    taL[w >> 1][1][lg * 4 + i][lc] = aB[i] + btbc;
                }
            }
            __syncthreads();
            if (!isOdd) {   // ff1, ff2 + gate -> xpose[:, 0:32]
                float tsv[4];
#pragma unroll
                for (int i = 0; i < 4; ++i)
                    tsv[i] = ts[(size_t)(r0 + lg * 4 + i) * Tt + t];
#pragma unroll
                for (int i = 0; i < 4; ++i) {
                    int row = lg * 4 + i;
                    float ff1 = fast_tanh(aA[i] + bf1c);
                    float ff2 = fast_tanh(aB[i] + bf2c);
                    float ta = taL[w >> 1][0][row][lc];
                    float tb = taL[w >> 1][1][row][lc];
                    float s = fast_sigmoid(ta * (tsv[i] * (1.0f / 256.0f)) + tb);
                    xpose[row][(w >> 1) * 16 + lc] = (_Float16)(ff1 + s * (ff2 - ff1));
                }
            }
            __syncthreads();
            if (tid < 64) {
                int row = tid >> 2, seg = tid & 3;
                f16x8 v = *(const f16x8*)&xpose[row][seg * 8];
                stg16_sys(hg + row * Hh + cb * 32 + seg * 8, v);
            }
        }
        cl_sync(flags, cb, t * 3 + 3, tid);
        // ---------- phase 4: h frags; x(t+1) prefetch; out(t) ----------
        {
            LD8_FRAGS(hfrag, hg + lc * Hh + lg * 8);
            if (t + 1 < Tt) {
                const float* xr = x + ((size_t)(r0 + lc) * Tt + (t + 1)) * Ff + lg * 8;
#pragma unroll
                for (int kt = 0; kt < 4; ++kt) {
                    f32x4 xa = *(const f32x4*)(xr + kt * 32);
                    f32x4 xb = *(const f32x4*)(xr + kt * 32 + 4);
                    f16x8 af;
#pragma unroll
                    for (int q = 0; q < 4; ++q) { af[q] = (_Float16)xa[q]; af[4 + q] = (_Float16)xb[q]; }
                    xf[kt] = af;
                }
            }
            if (w == 0) {
                f32x4 aA = {0.f,0.f,0.f,0.f}, aB = {0.f,0.f,0.f,0.f};
#pragma unroll
                for (int kt = 0; kt < 8; ++kt) {
                    if (kt & 1) aB = __builtin_amdgcn_mfma_f32_16x16x32_f16(hfrag[kt], wof[kt], aB, 0, 0, 0);
                    else        aA = __builtin_amdgcn_mfma_f32_16x16x32_f16(hfrag[kt], wof[kt], aA, 0, 0, 0);
                }
#pragma unroll
                for (int i = 0; i < 4; ++i)
                    out[((size_t)(r0 + lg * 4 + i) * Tt + t) * OUTo + colO] = aA[i] + aB[i] + boc;
            }
        }
        // next-step z1 writes are ordered behind the ph3 flag sync
    }
}

extern "C" void kernel_launch(void* const* d_in, const int* in_sizes, int n_in,
                              void* d_out, int out_size, void* d_ws, size_t ws_size,
                              hipStream_t stream) {
    const float* x    = (const float*)d_in[0];
    const float* ts   = (const float*)d_in[1];
    const float* W1   = (const float*)d_in[2];
    const float* b1   = (const float*)d_in[3];
    const float* W2   = (const float*)d_in[4];
    const float* b2   = (const float*)d_in[5];
    const float* Wff1 = (const float*)d_in[6];
    const float* bff1 = (const float*)d_in[7];
    const float* Wff2 = (const float*)d_in[8];
    const float* bff2 = (const float*)d_in[9];
    const float* Wta  = (const float*)d_in[10];
    const float* bta  = (const float*)d_in[11];
    const float* Wtb  = (const float*)d_in[12];
    const float* btb  = (const float*)d_in[13];
    const float* Wout = (const float*)d_in[14];
    const float* bout = (const float*)d_in[15];
    float* out = (float*)d_out;

    _Float16* wf = (_Float16*)d_ws;
    char* act = (char*)d_ws + ACT_OFF;
    int* cnt = (int*)((char*)d_ws + CNT_OFF);

    hipMemsetAsync(cnt, 0, CNT_BYTES, stream);
    prep_weights<<<(NFRAG * 512) / 256, 256, 0, stream>>>(W1, W2, Wff1, Wff2, Wta, Wtb, Wout, wf);
    cfc_main<<<NCLUST * CBLK, 256, 0, stream>>>(x, ts, b1, b2, bff1, bff2, bta, btb, bout,
                                                wf, act, cnt, out);
}